// Round 1
// baseline (581.499 us; speedup 1.0000x reference)
//
#include <hip/hip_runtime.h>

typedef _Float16 f16;
typedef _Float16 f16x4 __attribute__((ext_vector_type(4)));
typedef _Float16 f16x8 __attribute__((ext_vector_type(8)));
typedef float    f32x4 __attribute__((ext_vector_type(4)));

#define B_ 4
#define T_ 2048
#define C_ 1024
#define H_ 16
#define D_ 64

__device__ __forceinline__ void gload_lds16(const f16* g, f16* l) {
  __builtin_amdgcn_global_load_lds(
      (const __attribute__((address_space(1))) unsigned int*)g,
      (__attribute__((address_space(3))) unsigned int*)l, 16, 0, 0);
}

// ---------------- prep kernels ----------------
__global__ void cvt_kernel(const float* __restrict__ in, f16* __restrict__ out, int n4) {
  int i = blockIdx.x * blockDim.x + threadIdx.x;
  int stride = gridDim.x * blockDim.x;
  for (; i < n4; i += stride) {
    float4 v = ((const float4*)in)[i];
    f16x4 h = { (f16)v.x, (f16)v.y, (f16)v.z, (f16)v.w };
    ((f16x4*)out)[i] = h;
  }
}

// Wt[n][k] = (f16)W[k][n]   (W is [K,N] row-major)
__global__ void transpose_cvt_kernel(const float* __restrict__ W, f16* __restrict__ Wt,
                                     int K, int N) {
  __shared__ f16 tile[32][33];
  int bx = blockIdx.x, by = blockIdx.y;
  int tx = threadIdx.x & 31, ty = threadIdx.x >> 5;  // 32 x 8
  #pragma unroll
  for (int i = ty; i < 32; i += 8)
    tile[i][tx] = (f16)W[(size_t)(by * 32 + i) * N + bx * 32 + tx];
  __syncthreads();
  #pragma unroll
  for (int i = ty; i < 32; i += 8)
    Wt[(size_t)(bx * 32 + i) * K + by * 32 + tx] = tile[tx][i];
}

// ---------------- GEMM: C = A[M,K] * Bt[N,K]^T + bias ----------------
// EPI 0: scatter to Q/K/Vt (f16).  EPI 1: fp32 out[m*N+n].
template <int EPI>
__global__ __launch_bounds__(256, 2)
void gemm_kernel(const f16* __restrict__ A, const f16* __restrict__ Bt,
                 const float* __restrict__ bias, float* __restrict__ outF,
                 f16* __restrict__ q, f16* __restrict__ kk, f16* __restrict__ vt,
                 int M, int N, int K) {
  __shared__ __align__(16) f16 As[2][128 * 32];
  __shared__ __align__(16) f16 Bs[2][128 * 32];
  const int nbn = N >> 7;
  const int bid = blockIdx.x;
  const int bm = bid / nbn, bn = bid % nbn;
  const int m0 = bm << 7, n0 = bn << 7;
  const int tid = threadIdx.x;
  const int lane = tid & 63, wid = tid >> 6;
  const int wr = wid >> 1, wc = wid & 1;

  f32x4 acc[4][4] = {};

  // staging geometry: chunk c (1KB) = rows c*16..c*16+15, lane i -> row c*16+i/4, k-off (i%4)*8
  const int srow = lane >> 2;
  const int scol = (lane & 3) << 3;
  const f16* Abase = A + (size_t)(m0 + srow) * K + scol;
  const f16* Bbase = Bt + (size_t)(n0 + srow) * K + scol;

  auto stage = [&](int buf, int kt) {
    const int c0 = wid * 2;
    #pragma unroll
    for (int c = c0; c < c0 + 2; ++c) {
      gload_lds16(Abase + (size_t)c * 16 * K + kt * 32, &As[buf][c * 512]);
      gload_lds16(Bbase + (size_t)c * 16 * K + kt * 32, &Bs[buf][c * 512]);
    }
  };

  const int ko = (lane >> 4) << 3;
  const int rr = lane & 15;

  auto compute = [&](int buf) {
    f16x8 af[4], bf[4];
    #pragma unroll
    for (int t = 0; t < 4; ++t) {
      af[t] = *(const f16x8*)&As[buf][(wr * 64 + t * 16 + rr) * 32 + ko];
      bf[t] = *(const f16x8*)&Bs[buf][(wc * 64 + t * 16 + rr) * 32 + ko];
    }
    #pragma unroll
    for (int i = 0; i < 4; ++i)
      #pragma unroll
      for (int j = 0; j < 4; ++j)
        acc[i][j] = __builtin_amdgcn_mfma_f32_16x16x32_f16(af[i], bf[j], acc[i][j], 0, 0, 0);
  };

  const int nk = K >> 5;
  int cur = 0;
  stage(0, 0);
  __syncthreads();
  for (int kt = 0; kt < nk; ++kt) {
    if (kt + 1 < nk) stage(cur ^ 1, kt + 1);
    compute(cur);
    __syncthreads();
    cur ^= 1;
  }

  // epilogue: C/D layout col=lane&15, row=(lane>>4)*4+reg  [m89-verified]
  const int col = lane & 15;
  const int row4 = (lane >> 4) << 2;
  #pragma unroll
  for (int i = 0; i < 4; ++i) {
    #pragma unroll
    for (int j = 0; j < 4; ++j) {
      const int n = n0 + wc * 64 + j * 16 + col;
      const float bn_ = bias[n];
      #pragma unroll
      for (int r = 0; r < 4; ++r) {
        const int m = m0 + wr * 64 + i * 16 + row4 + r;
        const float v = acc[i][j][r] + bn_;
        if (EPI == 1) {
          outF[(size_t)m * N + n] = v;
        } else {
          const int which = n >> 10;           // 0=q 1=k 2=v
          const int cc = n & 1023;
          const int h = cc >> 6, d = cc & 63;
          const int b = m >> 11, t = m & 2047;
          const size_t bh = (size_t)b * 16 + h;
          const f16 hv = (f16)v;
          if (which == 0)      q [(bh * T_ + t) * D_ + d] = hv;
          else if (which == 1) kk[(bh * T_ + t) * D_ + d] = hv;
          else                 vt[(bh * D_ + d) * T_ + t] = hv;  // V transposed
        }
      }
    }
  }
}

// ---------------- causal flash attention ----------------
// grid = 64 bh * 32 q-tiles; block 256 = 4 waves * 16 q-rows each; KVBLK=64
__global__ __launch_bounds__(256, 2)
void attn_kernel(const f16* __restrict__ Q, const f16* __restrict__ Kg,
                 const f16* __restrict__ Vt, f16* __restrict__ Aout) {
  __shared__ __align__(16) f16 Plds[4][16][72];  // per-wave P tile, +8 pad
  const int bid = blockIdx.x;
  const int qi = bid & 31, bh = bid >> 5;
  const int lane = threadIdx.x & 63, w = threadIdx.x >> 6;
  const int qb = qi << 6;
  const int col = lane & 15;
  const int ko = (lane >> 4) << 3;
  const int row4 = (lane >> 4) << 2;

  const f16* Qp = Q + (size_t)bh * T_ * D_;
  const f16* Kp = Kg + (size_t)bh * T_ * D_;
  const f16* Vp = Vt + (size_t)bh * D_ * T_;

  const int qrow0 = qb + w * 16;

  f16x8 qf[2];
  #pragma unroll
  for (int s = 0; s < 2; ++s)
    qf[s] = *(const f16x8*)&Qp[(size_t)(qrow0 + col) * D_ + s * 32 + ko];

  f32x4 o[4] = {};
  float mrow[4], lrow[4];
  #pragma unroll
  for (int r = 0; r < 4; ++r) { mrow[r] = -1e30f; lrow[r] = 0.f; }

  const int nkt = qi + 1;
  for (int kt = 0; kt < nkt; ++kt) {
    const int kb = kt << 6;
    f32x4 sc[4] = {};
    #pragma unroll
    for (int s = 0; s < 2; ++s)
      #pragma unroll
      for (int nt = 0; nt < 4; ++nt) {
        f16x8 kf = *(const f16x8*)&Kp[(size_t)(kb + nt * 16 + col) * D_ + s * 32 + ko];
        sc[nt] = __builtin_amdgcn_mfma_f32_16x16x32_f16(qf[s], kf, sc[nt], 0, 0, 0);
      }

    // scale + causal mask (only diagonal tile needs it)
    #pragma unroll
    for (int nt = 0; nt < 4; ++nt)
      #pragma unroll
      for (int r = 0; r < 4; ++r) {
        float xv = sc[nt][r] * 0.125f;
        if (kt == qi) {
          const int qg = qrow0 + row4 + r;
          const int kg = kb + nt * 16 + col;
          if (kg > qg) xv = -1e30f;
        }
        sc[nt][r] = xv;
      }

    float rmax[4];
    #pragma unroll
    for (int r = 0; r < 4; ++r)
      rmax[r] = fmaxf(fmaxf(sc[0][r], sc[1][r]), fmaxf(sc[2][r], sc[3][r]));
    #pragma unroll
    for (int off = 1; off < 16; off <<= 1)
      #pragma unroll
      for (int r = 0; r < 4; ++r)
        rmax[r] = fmaxf(rmax[r], __shfl_xor(rmax[r], off, 64));

    #pragma unroll
    for (int r = 0; r < 4; ++r) {
      const float mnew = fmaxf(mrow[r], rmax[r]);
      const float alpha = __expf(mrow[r] - mnew);
      mrow[r] = mnew;
      lrow[r] *= alpha;
      #pragma unroll
      for (int nt = 0; nt < 4; ++nt) o[nt][r] *= alpha;
    }

    float rs[4] = {0.f, 0.f, 0.f, 0.f};
    #pragma unroll
    for (int nt = 0; nt < 4; ++nt)
      #pragma unroll
      for (int r = 0; r < 4; ++r) {
        const float p = __expf(sc[nt][r] - mrow[r]);
        rs[r] += p;
        Plds[w][row4 + r][nt * 16 + col] = (f16)p;
      }
    #pragma unroll
    for (int off = 1; off < 16; off <<= 1)
      #pragma unroll
      for (int r = 0; r < 4; ++r)
        rs[r] += __shfl_xor(rs[r], off, 64);
    #pragma unroll
    for (int r = 0; r < 4; ++r) lrow[r] += rs[r];

    // PV: A = P (LDS round-trip transpose), B = Vt rows (contiguous kv)
    #pragma unroll
    for (int s = 0; s < 2; ++s) {
      f16x8 pf = *(const f16x8*)&Plds[w][col][s * 32 + ko];
      #pragma unroll
      for (int nt = 0; nt < 4; ++nt) {
        f16x8 vf = *(const f16x8*)&Vp[(size_t)(nt * 16 + col) * T_ + kb + s * 32 + ko];
        o[nt] = __builtin_amdgcn_mfma_f32_16x16x32_f16(pf, vf, o[nt], 0, 0, 0);
      }
    }
  }

  const int b = bh >> 4, h = bh & 15;
  #pragma unroll
  for (int r = 0; r < 4; ++r) {
    const float inv = 1.0f / lrow[r];
    const int t = qrow0 + row4 + r;
    const size_t rowoff = ((size_t)b * T_ + t) * C_ + (size_t)h * D_;
    #pragma unroll
    for (int nt = 0; nt < 4; ++nt)
      Aout[rowoff + nt * 16 + col] = (f16)(o[nt][r] * inv);
  }
}

// ---------------- launch ----------------
extern "C" void kernel_launch(void* const* d_in, const int* in_sizes, int n_in,
                              void* d_out, int out_size, void* d_ws, size_t ws_size,
                              hipStream_t stream) {
  const float* x    = (const float*)d_in[0];
  const float* Wqkv = (const float*)d_in[1];
  const float* bqkv = (const float*)d_in[2];
  const float* Wout = (const float*)d_in[3];
  const float* bout = (const float*)d_in[4];
  float* out = (float*)d_out;

  char* ws = (char*)d_ws;
  f16* xb     = (f16*)ws;                   // 16MB (x in f16; later reused as Aout)
  f16* Wqkv_t = (f16*)(ws + (16u << 20));   // 6MB  [3072,1024]
  f16* Wout_t = (f16*)(ws + (22u << 20));   // 2MB  [1024,1024]
  f16* Qb     = (f16*)(ws + (24u << 20));   // 16MB [B,H,T,D]
  f16* Kb     = (f16*)(ws + (40u << 20));   // 16MB [B,H,T,D]
  f16* Vtb    = (f16*)(ws + (56u << 20));   // 16MB [B,H,D,T]  (total 72MB)

  cvt_kernel<<<2048, 256, 0, stream>>>(x, xb, (B_ * T_ * C_) / 4);
  dim3 g1(3072 / 32, 1024 / 32);
  transpose_cvt_kernel<<<g1, 256, 0, stream>>>(Wqkv, Wqkv_t, 1024, 3072);
  dim3 g2(1024 / 32, 1024 / 32);
  transpose_cvt_kernel<<<g2, 256, 0, stream>>>(Wout, Wout_t, 1024, 1024);

  gemm_kernel<0><<<64 * 24, 256, 0, stream>>>(xb, Wqkv_t, bqkv, nullptr,
                                              Qb, Kb, Vtb, 8192, 3072, 1024);
  attn_kernel<<<64 * 32, 256, 0, stream>>>(Qb, Kb, Vtb, xb /*Aout alias*/);
  gemm_kernel<1><<<64 * 8, 256, 0, stream>>>(xb, Wout_t, bout, out,
                                             nullptr, nullptr, nullptr, 8192, 1024, 1024);
}

// Round 2
// 246.207 us; speedup vs baseline: 2.3618x; 2.3618x over previous
//
#include <hip/hip_runtime.h>

typedef _Float16 f16;
typedef _Float16 f16x4 __attribute__((ext_vector_type(4)));
typedef _Float16 f16x8 __attribute__((ext_vector_type(8)));
typedef float    f32x4 __attribute__((ext_vector_type(4)));

#define B_ 4
#define T_ 2048
#define C_ 1024
#define H_ 16
#define D_ 64

__device__ __forceinline__ void gload_lds16(const f16* g, f16* l) {
  __builtin_amdgcn_global_load_lds(
      (const __attribute__((address_space(1))) unsigned int*)g,
      (__attribute__((address_space(3))) unsigned int*)l, 16, 0, 0);
}

// ---------------- prep kernels ----------------
__global__ void cvt_kernel(const float* __restrict__ in, f16* __restrict__ out, int n4) {
  int i = blockIdx.x * blockDim.x + threadIdx.x;
  int stride = gridDim.x * blockDim.x;
  for (; i < n4; i += stride) {
    float4 v = ((const float4*)in)[i];
    f16x4 h = { (f16)v.x, (f16)v.y, (f16)v.z, (f16)v.w };
    ((f16x4*)out)[i] = h;
  }
}

// Wt[n][k] = (f16)W[k][n]   (W is [K,N] row-major)
__global__ void transpose_cvt_kernel(const float* __restrict__ W, f16* __restrict__ Wt,
                                     int K, int N) {
  __shared__ f16 tile[32][33];
  int bx = blockIdx.x, by = blockIdx.y;
  int tx = threadIdx.x & 31, ty = threadIdx.x >> 5;  // 32 x 8
  #pragma unroll
  for (int i = ty; i < 32; i += 8)
    tile[i][tx] = (f16)W[(size_t)(by * 32 + i) * N + bx * 32 + tx];
  __syncthreads();
  #pragma unroll
  for (int i = ty; i < 32; i += 8)
    Wt[(size_t)(bx * 32 + i) * K + by * 32 + tx] = tile[tx][i];
}

// ---------------- GEMM: C = A[M,K] * Bt[N,K]^T + bias ----------------
template <int EPI>
__global__ __launch_bounds__(256, 2)
void gemm_kernel(const f16* __restrict__ A, const f16* __restrict__ Bt,
                 const float* __restrict__ bias, float* __restrict__ outF,
                 f16* __restrict__ q, f16* __restrict__ kk, f16* __restrict__ vt,
                 int M, int N, int K) {
  __shared__ __align__(16) f16 As[2][128 * 32];
  __shared__ __align__(16) f16 Bs[2][128 * 32];
  const int nbn = N >> 7;
  const int bid = blockIdx.x;
  const int bm = bid / nbn, bn = bid % nbn;
  const int m0 = bm << 7, n0 = bn << 7;
  const int tid = threadIdx.x;
  const int lane = tid & 63, wid = tid >> 6;
  const int wr = wid >> 1, wc = wid & 1;

  f32x4 acc[4][4] = {};

  const int srow = lane >> 2;
  const int scol = (lane & 3) << 3;
  const f16* Abase = A + (size_t)(m0 + srow) * K + scol;
  const f16* Bbase = Bt + (size_t)(n0 + srow) * K + scol;

  auto stage = [&](int buf, int kt) {
    const int c0 = wid * 2;
    #pragma unroll
    for (int c = c0; c < c0 + 2; ++c) {
      gload_lds16(Abase + (size_t)c * 16 * K + kt * 32, &As[buf][c * 512]);
      gload_lds16(Bbase + (size_t)c * 16 * K + kt * 32, &Bs[buf][c * 512]);
    }
  };

  const int ko = (lane >> 4) << 3;
  const int rr = lane & 15;

  auto compute = [&](int buf) {
    f16x8 af[4], bf[4];
    #pragma unroll
    for (int t = 0; t < 4; ++t) {
      af[t] = *(const f16x8*)&As[buf][(wr * 64 + t * 16 + rr) * 32 + ko];
      bf[t] = *(const f16x8*)&Bs[buf][(wc * 64 + t * 16 + rr) * 32 + ko];
    }
    #pragma unroll
    for (int i = 0; i < 4; ++i)
      #pragma unroll
      for (int j = 0; j < 4; ++j)
        acc[i][j] = __builtin_amdgcn_mfma_f32_16x16x32_f16(af[i], bf[j], acc[i][j], 0, 0, 0);
  };

  const int nk = K >> 5;
  int cur = 0;
  stage(0, 0);
  __syncthreads();
  for (int kt = 0; kt < nk; ++kt) {
    if (kt + 1 < nk) stage(cur ^ 1, kt + 1);
    compute(cur);
    __syncthreads();
    cur ^= 1;
  }

  const int col = lane & 15;
  const int row4 = (lane >> 4) << 2;
  #pragma unroll
  for (int i = 0; i < 4; ++i) {
    #pragma unroll
    for (int j = 0; j < 4; ++j) {
      const int n = n0 + wc * 64 + j * 16 + col;
      const float bn_ = bias[n];
      #pragma unroll
      for (int r = 0; r < 4; ++r) {
        const int m = m0 + wr * 64 + i * 16 + row4 + r;
        const float v = acc[i][j][r] + bn_;
        if (EPI == 1) {
          outF[(size_t)m * N + n] = v;
        } else {
          const int which = n >> 10;           // 0=q 1=k 2=v
          const int cc = n & 1023;
          const int h = cc >> 6, d = cc & 63;
          const int b = m >> 11, t = m & 2047;
          const size_t bh = (size_t)b * 16 + h;
          const f16 hv = (f16)v;
          if (which == 0)      q [(bh * T_ + t) * D_ + d] = hv;
          else if (which == 1) kk[(bh * T_ + t) * D_ + d] = hv;
          else                 vt[(bh * D_ + d) * T_ + t] = hv;  // V transposed
        }
      }
    }
  }
}

// ---------------- causal flash attention ----------------
// grid = 512: bh = bid&63 (XCD-clustered), pair = bid>>6 in [0,8)
// block 512 = 8 waves * 16 q-rows = 128-row q-tile; two tiles (pair, 15-pair)
// processed sequentially -> uniform 34 kt-iterations per block.
// K/V staged in LDS (dbuf, global_load_lds w16, XOR-swizzled via pre-swizzled src).
__global__ __launch_bounds__(512, 2)
void attn_kernel(const f16* __restrict__ Q, const f16* __restrict__ Kg,
                 const f16* __restrict__ Vt, f16* __restrict__ Aout) {
  __shared__ __align__(16) f16 Ks[2][64 * 64];   // [kvrow][d], rows 128B, swizzled
  __shared__ __align__(16) f16 Vs[2][64 * 64];   // [d][kv],   rows 128B, swizzled
  __shared__ __align__(16) f16 Plds[8][16][72];  // per-wave P tile, +8 pad

  const int bid = blockIdx.x;
  const int bh = bid & 63, pair = bid >> 6;
  const int lane = threadIdx.x & 63, w = threadIdx.x >> 6;
  const int col = lane & 15;
  const int g = lane >> 4;
  const int ko = g << 3;
  const int row4 = g << 2;

  const f16* Qp = Q + (size_t)bh * T_ * D_;
  const f16* Kp = Kg + (size_t)bh * T_ * D_;
  const f16* Vp = Vt + (size_t)bh * D_ * T_;

  // staging geometry: wave w stages chunk w (1KB) of K and of V.
  // lane i -> LDS byte w*1024 + i*16 -> row w*8 + (i>>3), phys colbyte (i&7)*16.
  // source colbyte = phys ^ ((row&7)<<4), row&7 == i>>3.
  const int srow8 = lane >> 3;                       // row&7
  const int scb = ((lane & 7) << 4) ^ (srow8 << 4);  // source colbyte
  const int krow_s = (w << 3) + srow8;               // row within 64-tile

  auto stage = [&](int buf, int kb) {
    gload_lds16(Kp + (size_t)(kb + krow_s) * D_ + (scb >> 1), &Ks[buf][w * 512]);
    gload_lds16(Vp + (size_t)krow_s * T_ + kb + (scb >> 1), &Vs[buf][w * 512]);
  };

  auto ldsK = [&](int buf, int krow, int d0) -> f16x8 {
    const int off = krow * 128 + ((d0 << 1) ^ ((krow & 7) << 4));
    return *(const f16x8*)((const char*)&Ks[buf][0] + off);
  };
  auto ldsV = [&](int buf, int drow, int k0) -> f16x8 {
    const int off = drow * 128 + ((k0 << 1) ^ ((drow & 7) << 4));
    return *(const f16x8*)((const char*)&Vs[buf][0] + off);
  };

  const int b = bh >> 4, h = bh & 15;

  #pragma unroll
  for (int tt = 0; tt < 2; ++tt) {
    const int ti = (tt == 0) ? pair : (15 - pair);
    const int q0 = ti << 7;
    const int qrow0 = q0 + (w << 4);
    const int nkt = (ti << 1) + 2;

    f16x8 qf[2];
    #pragma unroll
    for (int s = 0; s < 2; ++s)
      qf[s] = *(const f16x8*)&Qp[(size_t)(qrow0 + col) * D_ + s * 32 + ko];

    f32x4 o[4] = {};
    float mrow[4], lrow[4];
    #pragma unroll
    for (int r = 0; r < 4; ++r) { mrow[r] = -1e30f; lrow[r] = 0.f; }

    stage(0, 0);
    __syncthreads();
    int cur = 0;
    for (int kt = 0; kt < nkt; ++kt) {
      const int kb = kt << 6;
      if (kt + 1 < nkt) stage(cur ^ 1, (kt + 1) << 6);

      if (kb <= qrow0 + 15) {  // wave not fully masked
        f32x4 sc[4] = {};
        #pragma unroll
        for (int s = 0; s < 2; ++s)
          #pragma unroll
          for (int nt = 0; nt < 4; ++nt) {
            f16x8 kf = ldsK(cur, nt * 16 + col, s * 32 + ko);
            sc[nt] = __builtin_amdgcn_mfma_f32_16x16x32_f16(qf[s], kf, sc[nt], 0, 0, 0);
          }

        const bool needMask = (kb + 63 > qrow0);
        #pragma unroll
        for (int nt = 0; nt < 4; ++nt)
          #pragma unroll
          for (int r = 0; r < 4; ++r) {
            float xv = sc[nt][r] * 0.125f;
            if (needMask) {
              const int qg = qrow0 + row4 + r;
              const int kg = kb + nt * 16 + col;
              if (kg > qg) xv = -1e30f;
            }
            sc[nt][r] = xv;
          }

        float rmax[4];
        #pragma unroll
        for (int r = 0; r < 4; ++r)
          rmax[r] = fmaxf(fmaxf(sc[0][r], sc[1][r]), fmaxf(sc[2][r], sc[3][r]));
        #pragma unroll
        for (int off = 1; off < 16; off <<= 1)
          #pragma unroll
          for (int r = 0; r < 4; ++r)
            rmax[r] = fmaxf(rmax[r], __shfl_xor(rmax[r], off, 64));

        #pragma unroll
        for (int r = 0; r < 4; ++r) {
          const float mnew = fmaxf(mrow[r], rmax[r]);
          const float alpha = __expf(mrow[r] - mnew);
          mrow[r] = mnew;
          lrow[r] *= alpha;
          #pragma unroll
          for (int nt = 0; nt < 4; ++nt) o[nt][r] *= alpha;
        }

        float rs[4] = {0.f, 0.f, 0.f, 0.f};
        #pragma unroll
        for (int nt = 0; nt < 4; ++nt)
          #pragma unroll
          for (int r = 0; r < 4; ++r) {
            const float p = __expf(sc[nt][r] - mrow[r]);
            rs[r] += p;
            Plds[w][row4 + r][nt * 16 + col] = (f16)p;
          }
        #pragma unroll
        for (int off = 1; off < 16; off <<= 1)
          #pragma unroll
          for (int r = 0; r < 4; ++r)
            rs[r] += __shfl_xor(rs[r], off, 64);
        #pragma unroll
        for (int r = 0; r < 4; ++r) lrow[r] += rs[r];

        // PV: A = P (per-wave LDS transpose), B = Vt rows from swizzled LDS
        #pragma unroll
        for (int s = 0; s < 2; ++s) {
          f16x8 pf = *(const f16x8*)&Plds[w][col][s * 32 + ko];
          #pragma unroll
          for (int nt = 0; nt < 4; ++nt) {
            f16x8 vf = ldsV(cur, nt * 16 + col, s * 32 + ko);
            o[nt] = __builtin_amdgcn_mfma_f32_16x16x32_f16(pf, vf, o[nt], 0, 0, 0);
          }
        }
      }

      __syncthreads();
      cur ^= 1;
    }

    #pragma unroll
    for (int r = 0; r < 4; ++r) {
      const float inv = 1.0f / lrow[r];
      const int t = qrow0 + row4 + r;
      const size_t rowoff = ((size_t)b * T_ + t) * C_ + (size_t)h * D_;
      #pragma unroll
      for (int nt = 0; nt < 4; ++nt)
        Aout[rowoff + nt * 16 + col] = (f16)(o[nt][r] * inv);
    }
    __syncthreads();
  }
}

// ---------------- launch ----------------
extern "C" void kernel_launch(void* const* d_in, const int* in_sizes, int n_in,
                              void* d_out, int out_size, void* d_ws, size_t ws_size,
                              hipStream_t stream) {
  const float* x    = (const float*)d_in[0];
  const float* Wqkv = (const float*)d_in[1];
  const float* bqkv = (const float*)d_in[2];
  const float* Wout = (const float*)d_in[3];
  const float* bout = (const float*)d_in[4];
  float* out = (float*)d_out;

  char* ws = (char*)d_ws;
  f16* xb     = (f16*)ws;                   // 16MB (x in f16; later reused as Aout)
  f16* Wqkv_t = (f16*)(ws + (16u << 20));   // 6MB  [3072,1024]
  f16* Wout_t = (f16*)(ws + (22u << 20));   // 2MB  [1024,1024]
  f16* Qb     = (f16*)(ws + (24u << 20));   // 16MB [B,H,T,D]
  f16* Kb     = (f16*)(ws + (40u << 20));   // 16MB [B,H,T,D]
  f16* Vtb    = (f16*)(ws + (56u << 20));   // 16MB [B,H,D,T]

  cvt_kernel<<<2048, 256, 0, stream>>>(x, xb, (B_ * T_ * C_) / 4);
  dim3 g1(3072 / 32, 1024 / 32);
  transpose_cvt_kernel<<<g1, 256, 0, stream>>>(Wqkv, Wqkv_t, 1024, 3072);
  dim3 g2(1024 / 32, 1024 / 32);
  transpose_cvt_kernel<<<g2, 256, 0, stream>>>(Wout, Wout_t, 1024, 1024);

  gemm_kernel<0><<<64 * 24, 256, 0, stream>>>(xb, Wqkv_t, bqkv, nullptr,
                                              Qb, Kb, Vtb, 8192, 3072, 1024);
  attn_kernel<<<512, 512, 0, stream>>>(Qb, Kb, Vtb, xb /*Aout alias*/);
  gemm_kernel<1><<<64 * 8, 256, 0, stream>>>(xb, Wout_t, bout, out,
                                             nullptr, nullptr, nullptr, 8192, 1024, 1024);
}

// Round 3
// 227.217 us; speedup vs baseline: 2.5592x; 1.0836x over previous
//
#include <hip/hip_runtime.h>

typedef _Float16 f16;
typedef _Float16 f16x4 __attribute__((ext_vector_type(4)));
typedef _Float16 f16x8 __attribute__((ext_vector_type(8)));
typedef float    f32x4 __attribute__((ext_vector_type(4)));

#define B_ 4
#define T_ 2048
#define C_ 1024
#define H_ 16
#define D_ 64

__device__ __forceinline__ void gload_lds16(const f16* g, f16* l) {
  __builtin_amdgcn_global_load_lds(
      (const __attribute__((address_space(1))) unsigned int*)g,
      (__attribute__((address_space(3))) unsigned int*)l, 16, 0, 0);
}

// ---------------- prep kernels ----------------
__global__ void cvt_kernel(const float* __restrict__ in, f16* __restrict__ out, int n4) {
  int i = blockIdx.x * blockDim.x + threadIdx.x;
  int stride = gridDim.x * blockDim.x;
  for (; i < n4; i += stride) {
    float4 v = ((const float4*)in)[i];
    f16x4 h = { (f16)v.x, (f16)v.y, (f16)v.z, (f16)v.w };
    ((f16x4*)out)[i] = h;
  }
}

// Wt[n][k] = (f16)W[k][n]   (W is [K,N] row-major)
__global__ void transpose_cvt_kernel(const float* __restrict__ W, f16* __restrict__ Wt,
                                     int K, int N) {
  __shared__ f16 tile[32][33];
  int bx = blockIdx.x, by = blockIdx.y;
  int tx = threadIdx.x & 31, ty = threadIdx.x >> 5;  // 32 x 8
  #pragma unroll
  for (int i = ty; i < 32; i += 8)
    tile[i][tx] = (f16)W[(size_t)(by * 32 + i) * N + bx * 32 + tx];
  __syncthreads();
  #pragma unroll
  for (int i = ty; i < 32; i += 8)
    Wt[(size_t)(bx * 32 + i) * K + by * 32 + tx] = tile[tx][i];
}

// ---------------- GEMM: C = A[M,K] * Bt[N,K]^T + bias ----------------
template <int EPI>
__global__ __launch_bounds__(256, 2)
void gemm_kernel(const f16* __restrict__ A, const f16* __restrict__ Bt,
                 const float* __restrict__ bias, float* __restrict__ outF,
                 f16* __restrict__ q, f16* __restrict__ kk, f16* __restrict__ vt,
                 int M, int N, int K) {
  __shared__ __align__(16) f16 As[2][128 * 32];
  __shared__ __align__(16) f16 Bs[2][128 * 32];
  const int nbn = N >> 7;
  const int bid = blockIdx.x;
  const int bm = bid / nbn, bn = bid % nbn;
  const int m0 = bm << 7, n0 = bn << 7;
  const int tid = threadIdx.x;
  const int lane = tid & 63, wid = tid >> 6;
  const int wr = wid >> 1, wc = wid & 1;

  f32x4 acc[4][4] = {};

  const int srow = lane >> 2;
  const int scol = (lane & 3) << 3;
  const f16* Abase = A + (size_t)(m0 + srow) * K + scol;
  const f16* Bbase = Bt + (size_t)(n0 + srow) * K + scol;

  auto stage = [&](int buf, int kt) {
    const int c0 = wid * 2;
    #pragma unroll
    for (int c = c0; c < c0 + 2; ++c) {
      gload_lds16(Abase + (size_t)c * 16 * K + kt * 32, &As[buf][c * 512]);
      gload_lds16(Bbase + (size_t)c * 16 * K + kt * 32, &Bs[buf][c * 512]);
    }
  };

  const int ko = (lane >> 4) << 3;
  const int rr = lane & 15;

  auto compute = [&](int buf) {
    f16x8 af[4], bf[4];
    #pragma unroll
    for (int t = 0; t < 4; ++t) {
      af[t] = *(const f16x8*)&As[buf][(wr * 64 + t * 16 + rr) * 32 + ko];
      bf[t] = *(const f16x8*)&Bs[buf][(wc * 64 + t * 16 + rr) * 32 + ko];
    }
    #pragma unroll
    for (int i = 0; i < 4; ++i)
      #pragma unroll
      for (int j = 0; j < 4; ++j)
        acc[i][j] = __builtin_amdgcn_mfma_f32_16x16x32_f16(af[i], bf[j], acc[i][j], 0, 0, 0);
  };

  const int nk = K >> 5;
  int cur = 0;
  stage(0, 0);
  __syncthreads();
  for (int kt = 0; kt < nk; ++kt) {
    if (kt + 1 < nk) stage(cur ^ 1, kt + 1);
    compute(cur);
    __syncthreads();
    cur ^= 1;
  }

  const int col = lane & 15;
  const int row4 = (lane >> 4) << 2;
  #pragma unroll
  for (int i = 0; i < 4; ++i) {
    #pragma unroll
    for (int j = 0; j < 4; ++j) {
      const int n = n0 + wc * 64 + j * 16 + col;
      const float bn_ = bias[n];
      #pragma unroll
      for (int r = 0; r < 4; ++r) {
        const int m = m0 + wr * 64 + i * 16 + row4 + r;
        const float v = acc[i][j][r] + bn_;
        if (EPI == 1) {
          outF[(size_t)m * N + n] = v;
        } else {
          const int which = n >> 10;           // 0=q 1=k 2=v
          const int cc = n & 1023;
          const int h = cc >> 6, d = cc & 63;
          const int b = m >> 11, t = m & 2047;
          const size_t bh = (size_t)b * 16 + h;
          const f16 hv = (f16)v;
          if (which == 0)      q [(bh * T_ + t) * D_ + d] = hv;
          else if (which == 1) kk[(bh * T_ + t) * D_ + d] = hv;
          else                 vt[(bh * D_ + d) * T_ + t] = hv;  // V transposed
        }
      }
    }
  }
}

// ---------------- causal flash attention ----------------
// grid = 1024. Bijective XCD swizzle: wgid = (bid&7)*128 + (bid>>3);
// bh = wgid>>4 (8 bh per XCD -> K/V fits XCD L2), ti = 15-(wgid&15)
// (longest tile dispatched first). Block = 8 waves * 16 q-rows = 128-row tile.
// Swapped QK^T: sc = mfma(K_frag, Q_frag) -> S^T, q-row = lane&15 lane-local.
// Softmax: in-lane over 16 kv + 2 shfl_xor(16,32). PV: O^T = mfma(V_frag, P_frag)
// with P^T staged per-wave via 4x ds_write_b64 / 2x ds_read_b128.
__global__ __launch_bounds__(512, 2)
void attn_kernel(const f16* __restrict__ Q, const f16* __restrict__ Kg,
                 const f16* __restrict__ Vt, f16* __restrict__ Aout) {
  __shared__ __align__(16) f16 Ks[2][64 * 64];   // [kvrow][d], rows 128B, swizzled
  __shared__ __align__(16) f16 Vs[2][64 * 64];   // [d][kv],   rows 128B, swizzled
  __shared__ __align__(16) f16 Pt[8][16][72];    // per-wave P^T tile [q][kv], +8 pad

  const int bid = blockIdx.x;
  const int wgid = (bid & 7) * 128 + (bid >> 3);
  const int bh = wgid >> 4;
  const int ti = 15 - (wgid & 15);
  const int lane = threadIdx.x & 63, w = threadIdx.x >> 6;
  const int col = lane & 15;
  const int g = lane >> 4;
  const int ko = g << 3;

  const f16* Qp = Q + (size_t)bh * T_ * D_;
  const f16* Kp = Kg + (size_t)bh * T_ * D_;
  const f16* Vp = Vt + (size_t)bh * D_ * T_;

  // staging geometry (wave w stages 1KB chunk w of K and of V):
  const int srow8 = lane >> 3;                       // row&7
  const int scb = ((lane & 7) << 4) ^ (srow8 << 4);  // pre-swizzled source colbyte
  const int krow_s = (w << 3) + srow8;

  auto stage = [&](int buf, int kb) {
    gload_lds16(Kp + (size_t)(kb + krow_s) * D_ + (scb >> 1), &Ks[buf][w * 512]);
    gload_lds16(Vp + (size_t)krow_s * T_ + kb + (scb >> 1), &Vs[buf][w * 512]);
  };
  auto ldsK = [&](int buf, int krow, int d0) -> f16x8 {
    const int off = krow * 128 + ((d0 << 1) ^ ((krow & 7) << 4));
    return *(const f16x8*)((const char*)&Ks[buf][0] + off);
  };
  auto ldsV = [&](int buf, int drow, int k0) -> f16x8 {
    const int off = drow * 128 + ((k0 << 1) ^ ((drow & 7) << 4));
    return *(const f16x8*)((const char*)&Vs[buf][0] + off);
  };

  const int q0 = ti << 7;
  const int qrow0 = q0 + (w << 4);
  const int nkt = (ti << 1) + 2;
  const int qg = qrow0 + col;          // this lane's q row (lane-local)

  // Q fragment (B-operand), pre-scaled by 1/sqrt(D)
  f16x8 qf[2];
  #pragma unroll
  for (int s = 0; s < 2; ++s) {
    f16x8 t = *(const f16x8*)&Qp[(size_t)qg * D_ + s * 32 + ko];
    #pragma unroll
    for (int e = 0; e < 8; ++e) t[e] = t[e] * (f16)0.125f;
    qf[s] = t;
  }

  f32x4 o[4] = {};
  float m = -1e30f, l = 0.f;

  stage(0, 0);
  __syncthreads();
  int cur = 0;
  for (int kt = 0; kt < nkt; ++kt) {
    const int kb = kt << 6;
    if (kt + 1 < nkt) stage(cur ^ 1, (kt + 1) << 6);

    if (kb <= qrow0 + 15) {  // wave has unmasked work
      // QK^T (swapped): sc[mt][r] = S[kv = kb+mt*16+g*4+r][q = qg]
      f32x4 sc[4] = {};
      #pragma unroll
      for (int s = 0; s < 2; ++s)
        #pragma unroll
        for (int mt = 0; mt < 4; ++mt) {
          f16x8 kf = ldsK(cur, mt * 16 + col, s * 32 + ko);
          sc[mt] = __builtin_amdgcn_mfma_f32_16x16x32_f16(kf, qf[s], sc[mt], 0, 0, 0);
        }

      const bool needMask = (kb + 63 > qrow0);
      if (needMask) {
        #pragma unroll
        for (int mt = 0; mt < 4; ++mt)
          #pragma unroll
          for (int r = 0; r < 4; ++r)
            if (kb + mt * 16 + (g << 2) + r > qg) sc[mt][r] = -1e30f;
      }

      // row max: in-lane over 16, then across the 4 lane-groups
      float mx = fmaxf(fmaxf(fmaxf(sc[0][0], sc[0][1]), fmaxf(sc[0][2], sc[0][3])),
                       fmaxf(fmaxf(sc[1][0], sc[1][1]), fmaxf(sc[1][2], sc[1][3])));
      mx = fmaxf(mx, fmaxf(fmaxf(fmaxf(sc[2][0], sc[2][1]), fmaxf(sc[2][2], sc[2][3])),
                           fmaxf(fmaxf(sc[3][0], sc[3][1]), fmaxf(sc[3][2], sc[3][3]))));
      mx = fmaxf(mx, __shfl_xor(mx, 16, 64));
      mx = fmaxf(mx, __shfl_xor(mx, 32, 64));

      // defer-rescale (T13): skip o-rescale while tile max stays within THR=8
      if (!__all(mx - m <= 8.f)) {
        const float mnew = fmaxf(m, mx);
        const float alpha = __expf(m - mnew);
        m = mnew;
        l *= alpha;
        #pragma unroll
        for (int mt = 0; mt < 4; ++mt)
          #pragma unroll
          for (int r = 0; r < 4; ++r) o[mt][r] *= alpha;
      }

      // P = exp(S - m); store P^T[q][kv] (4 kv-contiguous per reg -> b64 writes)
      float rs = 0.f;
      #pragma unroll
      for (int mt = 0; mt < 4; ++mt) {
        f16x4 ph;
        #pragma unroll
        for (int r = 0; r < 4; ++r) {
          const float p = __expf(sc[mt][r] - m);
          rs += p;
          ph[r] = (f16)p;
        }
        *(f16x4*)&Pt[w][col][mt * 16 + (g << 2)] = ph;
      }
      rs += __shfl_xor(rs, 16, 64);
      rs += __shfl_xor(rs, 32, 64);
      l += rs;

      // PV (swapped): o[mt][r] = O[q=qg][d = mt*16+g*4+r]
      #pragma unroll
      for (int s = 0; s < 2; ++s) {
        f16x8 pb = *(const f16x8*)&Pt[w][col][s * 32 + ko];
        #pragma unroll
        for (int mt = 0; mt < 4; ++mt) {
          f16x8 vf = ldsV(cur, mt * 16 + col, s * 32 + ko);
          o[mt] = __builtin_amdgcn_mfma_f32_16x16x32_f16(vf, pb, o[mt], 0, 0, 0);
        }
      }
    }

    __syncthreads();
    cur ^= 1;
  }

  const int b = bh >> 4, h = bh & 15;
  const float inv = 1.0f / l;
  const size_t rowoff = ((size_t)b * T_ + qg) * C_ + (size_t)h * D_;
  #pragma unroll
  for (int mt = 0; mt < 4; ++mt) {
    f16x4 ov;
    #pragma unroll
    for (int r = 0; r < 4; ++r) ov[r] = (f16)(o[mt][r] * inv);
    *(f16x4*)&Aout[rowoff + mt * 16 + (g << 2)] = ov;
  }
}

// ---------------- launch ----------------
extern "C" void kernel_launch(void* const* d_in, const int* in_sizes, int n_in,
                              void* d_out, int out_size, void* d_ws, size_t ws_size,
                              hipStream_t stream) {
  const float* x    = (const float*)d_in[0];
  const float* Wqkv = (const float*)d_in[1];
  const float* bqkv = (const float*)d_in[2];
  const float* Wout = (const float*)d_in[3];
  const float* bout = (const float*)d_in[4];
  float* out = (float*)d_out;

  char* ws = (char*)d_ws;
  f16* xb     = (f16*)ws;                   // 16MB (x in f16; later reused as Aout)
  f16* Wqkv_t = (f16*)(ws + (16u << 20));   // 6MB  [3072,1024]
  f16* Wout_t = (f16*)(ws + (22u << 20));   // 2MB  [1024,1024]
  f16* Qb     = (f16*)(ws + (24u << 20));   // 16MB [B,H,T,D]
  f16* Kb     = (f16*)(ws + (40u << 20));   // 16MB [B,H,T,D]
  f16* Vtb    = (f16*)(ws + (56u << 20));   // 16MB [B,H,D,T]

  cvt_kernel<<<2048, 256, 0, stream>>>(x, xb, (B_ * T_ * C_) / 4);
  dim3 g1(3072 / 32, 1024 / 32);
  transpose_cvt_kernel<<<g1, 256, 0, stream>>>(Wqkv, Wqkv_t, 1024, 3072);
  dim3 g2(1024 / 32, 1024 / 32);
  transpose_cvt_kernel<<<g2, 256, 0, stream>>>(Wout, Wout_t, 1024, 1024);

  gemm_kernel<0><<<64 * 24, 256, 0, stream>>>(xb, Wqkv_t, bqkv, nullptr,
                                              Qb, Kb, Vtb, 8192, 3072, 1024);
  attn_kernel<<<1024, 512, 0, stream>>>(Qb, Kb, Vtb, xb /*Aout alias*/);
  gemm_kernel<1><<<64 * 8, 256, 0, stream>>>(xb, Wout_t, bout, out,
                                             nullptr, nullptr, nullptr, 8192, 1024, 1024);
}